// Round 17
// baseline (390.511 us; speedup 1.0000x reference)
//
#include <hip/hip_runtime.h>
#include <hip/hip_bf16.h>
#include <hip/hip_fp16.h>
#include <cstdint>
#include <cstddef>

// Problem constants (from reference)
#define D_MODEL 1024
#define D_INNER 2048
#define NSTATE  16
#define DTRANK  64
#define BATCH   2
#define SEQLEN  2048
#define BL      (BATCH*SEQLEN)   // 4096 tokens
#define NSEG    64
#define TSEG    (SEQLEN/NSEG)    // 32
#define SKX     8                // split-K factor for x_proj
#define KCH     (D_INNER/SKX)    // 256
#define LOG2E   1.4426950408889634f

typedef __attribute__((ext_vector_type(8))) _Float16 f16x8;
typedef __attribute__((ext_vector_type(4))) float f32x4;

__device__ __forceinline__ float softplusf(float x) {
    return fmaxf(x, 0.f) + log1pf(expf(-fabsf(x)));
}
__device__ __forceinline__ unsigned short f2h(float x) {
    __half h = __float2half(x);
    return *(unsigned short*)&h;
}
__device__ __forceinline__ float h2f(unsigned short u) {
    __half h; *(unsigned short*)&h = u;
    return __half2float(h);
}
// async global->LDS, 16B per lane (dest must be linear: base + lane*16)
__device__ __forceinline__ void gll16(const void* g, void* l) {
    __builtin_amdgcn_global_load_lds(
        (const __attribute__((address_space(1))) void*)g,
        (__attribute__((address_space(3))) void*)l, 16, 0, 0);
}

// ---- fused: A16 row m = fp16(x row); LoRA dot -> ext cols [1024,1056) ----
__global__ __launch_bounds__(256) void fused_x16_kernel(
        const float* __restrict__ x, const float* __restrict__ lA,
        unsigned short* __restrict__ A16) {
    const int m = blockIdx.x, tid = threadIdx.x;
    float4 v = *(const float4*)(x + (size_t)m * 1024 + tid * 4);
    ushort4 hv = {f2h(v.x), f2h(v.y), f2h(v.z), f2h(v.w)};
    *(ushort4*)(A16 + (size_t)m * 1056 + tid * 4) = hv;
    float p[16];
    #pragma unroll
    for (int r = 0; r < 16; ++r) {
        float4 a = *(const float4*)(lA + (size_t)r * 1024 + tid * 4);
        p[r] = v.x * a.x + v.y * a.y + v.z * a.z + v.w * a.w;
    }
    #pragma unroll
    for (int r = 0; r < 16; ++r)
        #pragma unroll
        for (int o = 32; o; o >>= 1) p[r] += __shfl_xor(p[r], o);
    __shared__ float red[4][16];
    const int lane = tid & 63, wv = tid >> 6;
    if (lane == 0) {
        #pragma unroll
        for (int r = 0; r < 16; ++r) red[wv][r] = p[r];
    }
    __syncthreads();
    if (tid < 32) {
        float val = 0.f;
        if (tid < 16)
            val = (red[0][tid] + red[1][tid]) + (red[2][tid] + red[3][tid]);
        A16[(size_t)m * 1056 + 1024 + tid] = f2h(val);
    }
}

// ---- fused: W16 row n = fp16(w row); ext cols = lb[n][c]*mask[n]*2 ----
__global__ __launch_bounds__(256) void cvt16w_ext_kernel(
        const float* __restrict__ w, const float* __restrict__ lb,
        const float* __restrict__ mask, int K, int KP, int ncols,
        unsigned short* __restrict__ dst) {
    const int n = blockIdx.x, tid = threadIdx.x;
    for (int k = tid * 4; k < K; k += 1024) {
        float4 v = *(const float4*)(w + (size_t)n * K + k);
        ushort4 h = {f2h(v.x), f2h(v.y), f2h(v.z), f2h(v.w)};
        *(ushort4*)(dst + (size_t)n * KP + k) = h;
    }
    if (tid < ncols) {
        float val = (tid < 16) ? lb[(size_t)n * 16 + tid] * mask[n] * 2.0f : 0.f;
        dst[(size_t)n * KP + K + tid] = f2h(val);
    }
}

// ---- fused: A16_out row = fp16(y row); LoRA dot -> ext cols [2048,2112) ----
__global__ __launch_bounds__(256) void fused_y16_kernel(
        const float* __restrict__ y, const float* __restrict__ lA,
        unsigned short* __restrict__ A16, int KP) {
    const int m = blockIdx.x, tid = threadIdx.x;
    const float* yr = y + (size_t)m * 2048;
    float4 v0 = *(const float4*)(yr + tid * 8);
    float4 v1 = *(const float4*)(yr + tid * 8 + 4);
    float yv[8] = {v0.x, v0.y, v0.z, v0.w, v1.x, v1.y, v1.z, v1.w};
    ushort4 h0 = {f2h(yv[0]), f2h(yv[1]), f2h(yv[2]), f2h(yv[3])};
    ushort4 h1 = {f2h(yv[4]), f2h(yv[5]), f2h(yv[6]), f2h(yv[7])};
    *(ushort4*)(A16 + (size_t)m * KP + tid * 8)     = h0;
    *(ushort4*)(A16 + (size_t)m * KP + tid * 8 + 4) = h1;
    float p[16];
    #pragma unroll
    for (int r = 0; r < 16; ++r) {
        const float* lr = lA + (size_t)r * 2048 + tid * 8;
        float4 a0 = *(const float4*)lr;
        float4 a1 = *(const float4*)(lr + 4);
        p[r] = yv[0]*a0.x + yv[1]*a0.y + yv[2]*a0.z + yv[3]*a0.w
             + yv[4]*a1.x + yv[5]*a1.y + yv[6]*a1.z + yv[7]*a1.w;
    }
    #pragma unroll
    for (int r = 0; r < 16; ++r)
        #pragma unroll
        for (int o = 32; o; o >>= 1) p[r] += __shfl_xor(p[r], o);
    __shared__ float red[4][16];
    const int lane = tid & 63, wv = tid >> 6;
    if (lane == 0) {
        #pragma unroll
        for (int r = 0; r < 16; ++r) red[wv][r] = p[r];
    }
    __syncthreads();
    if (tid < 64) {
        float val = 0.f;
        if (tid < 16)
            val = (red[0][tid] + red[1][tid]) + (red[2][tid] + red[3][tid]);
        A16[(size_t)m * KP + 2048 + tid] = f2h(val);
    }
}

// ---- fp16 convert with row padding: rows >= Msrc write zeros ----
__global__ __launch_bounds__(256) void cvtpad16_kernel(
        const float* __restrict__ src, int Msrc, int K4,
        unsigned short* __restrict__ dst, int total4) {
    int idx = blockIdx.x * 256 + threadIdx.x;
    if (idx >= total4) return;
    int m = idx / K4;
    int kq = idx - m * K4;
    ushort4 h = {0, 0, 0, 0};
    if (m < Msrc) {
        float4 v = *(const float4*)(src + (size_t)m * (K4 * 4) + kq * 4);
        h.x = f2h(v.x); h.y = f2h(v.y); h.z = f2h(v.z); h.w = f2h(v.w);
    }
    *(ushort4*)(dst + (size_t)m * (K4 * 4) + kq * 4) = h;
}

// ---- fused dt conversions: A16_dt from xdbl[:, :64], W16_dt from w_dt ----
__global__ __launch_bounds__(256) void cvt16dt_kernel(
        const float* __restrict__ xdbl, const float* __restrict__ w_dt,
        unsigned short* __restrict__ A16, unsigned short* __restrict__ W16) {
    int idx = blockIdx.x * 256 + threadIdx.x;
    if (idx < 4096 * 16) {
        int m = idx >> 4, kq = idx & 15;
        float4 v = *(const float4*)(xdbl + (size_t)m * 96 + kq * 4);
        ushort4 h = {f2h(v.x), f2h(v.y), f2h(v.z), f2h(v.w)};
        *(ushort4*)(A16 + (size_t)m * 64 + kq * 4) = h;
    } else {
        int j = idx - 4096 * 16;
        if (j >= 2048 * 16) return;
        int m = j >> 4, kq = j & 15;
        float4 v = *(const float4*)(w_dt + (size_t)m * 64 + kq * 4);
        ushort4 h = {f2h(v.x), f2h(v.y), f2h(v.z), f2h(v.w)};
        *(ushort4*)(W16 + (size_t)m * 64 + kq * 4) = h;
    }
}

// ---- 256x256 fp16 MFMA GEMM, BK=32, 2-phase dbuf, fp16 store ----
// 512 threads = 8 waves (2M x 4N), 128x64 output per wave, acc[8][4].
// LDS 64 KB (2 buf x (A 16KB + B 16KB)). Intensity 128 FLOP/staged-byte
// (2x the 128^2 kernel); B-panel HBM refetch halves.
__global__ __launch_bounds__(512, 1) void mfma_gemm16_256(
        const unsigned short* __restrict__ Ag, const unsigned short* __restrict__ Wg,
        int KP, unsigned short* __restrict__ C16, int ldc) {
    __shared__ __align__(16) short Ash[2][4][256][8];
    __shared__ __align__(16) short Wsh[2][4][256][8];
    const int tid = threadIdx.x;
    const int bn0 = blockIdx.x * 256, bm0 = blockIdx.y * 256;
    const int wave = tid >> 6, lane = tid & 63;
    const int wr = (wave >> 2) * 128, wc = (wave & 3) * 64;
    const int fr = lane & 15, fg = lane >> 4;
    const int KT = KP >> 5;
    const int srow = tid & 255, skg = tid >> 8;   // 0 or 1

    const unsigned short* pA = Ag + (size_t)(bm0 + srow) * KP + skg * 8;
    const unsigned short* pW = Wg + (size_t)(bn0 + srow) * KP + skg * 8;

    f32x4 acc[8][4];
    #pragma unroll
    for (int i = 0; i < 8; ++i)
        #pragma unroll
        for (int j = 0; j < 4; ++j) acc[i][j] = (f32x4){0.f, 0.f, 0.f, 0.f};

    auto stage = [&](int kt, int pb) {
        const int koff = kt * 32;
        gll16(pA + koff,      &Ash[pb][skg    ][srow][0]);
        gll16(pA + koff + 16, &Ash[pb][skg + 2][srow][0]);
        gll16(pW + koff,      &Wsh[pb][skg    ][srow][0]);
        gll16(pW + koff + 16, &Wsh[pb][skg + 2][srow][0]);
    };

    stage(0, 0);
    for (int kt = 0; kt < KT; ++kt) {
        const int cur = kt & 1;
        __syncthreads();   // drains vmcnt(0): buf[cur] staged; prev reads done
        if (kt + 1 < KT) stage(kt + 1, cur ^ 1);
        f16x8 a[8], w[4];
        #pragma unroll
        for (int i = 0; i < 8; ++i)
            a[i] = *(const f16x8*)&Ash[cur][fg][wr + i * 16 + fr][0];
        #pragma unroll
        for (int j = 0; j < 4; ++j)
            w[j] = *(const f16x8*)&Wsh[cur][fg][wc + j * 16 + fr][0];
        #pragma unroll
        for (int i = 0; i < 8; ++i)
            #pragma unroll
            for (int j = 0; j < 4; ++j)
                acc[i][j] = __builtin_amdgcn_mfma_f32_16x16x32_f16(a[i], w[j], acc[i][j], 0, 0, 0);
    }
    // C/D layout: col = lane&15, row = (lane>>4)*4 + q
    #pragma unroll
    for (int i = 0; i < 8; ++i) {
        #pragma unroll
        for (int j = 0; j < 4; ++j) {
            int n = bn0 + wc + j * 16 + fr;
            #pragma unroll
            for (int q = 0; q < 4; ++q) {
                int m = bm0 + wr + i * 16 + fg * 4 + q;
                C16[(size_t)m * ldc + n] = f2h(acc[i][j][q]);
            }
        }
    }
}

// ---- fp16 single-pass MFMA GEMM, BK=32, 2-phase dbuf, split-K + N bound ----
// EPI==0: f32 store. EPI==1: fp16 store. EPI==2: softplus(v+bias[n]) f32.
template<int EPI>
__global__ __launch_bounds__(256, 4) void mfma_gemm16(
        const unsigned short* __restrict__ Ag, const unsigned short* __restrict__ Wg,
        int KP, float* __restrict__ C, int ldc,
        const float* __restrict__ bias, int Nbound, int kchunk) {
    __shared__ __align__(16) short Ash[2][4][128][8];
    __shared__ __align__(16) short Wsh[2][4][128][8];
    const int tid = threadIdx.x;
    const int bn0 = blockIdx.x * 128, bm0 = blockIdx.y * 128;
    const int wave = tid >> 6, lane = tid & 63;
    const int wr = (wave >> 1) * 64, wc = (wave & 1) * 64;
    const int fr = lane & 15, fg = lane >> 4;
    int koff0 = 0, KT;
    if (kchunk) {
        koff0 = blockIdx.z * kchunk;
        KT = kchunk >> 5;
        C += (size_t)blockIdx.z * gridDim.y * 128 * ldc;
    } else {
        KT = KP >> 5;
    }
    const int srow = tid & 127, skg = tid >> 7;

    const unsigned short* pA = Ag + (size_t)(bm0 + srow) * KP + koff0 + skg * 8;
    const unsigned short* pW = Wg + (size_t)(bn0 + srow) * KP + koff0 + skg * 8;

    f32x4 acc[4][4];
    #pragma unroll
    for (int i = 0; i < 4; ++i)
        #pragma unroll
        for (int j = 0; j < 4; ++j) acc[i][j] = (f32x4){0.f, 0.f, 0.f, 0.f};

    auto stage = [&](int kt, int pb) {
        const int koff = kt * 32;
        gll16(pA + koff,      &Ash[pb][skg    ][srow][0]);
        gll16(pA + koff + 16, &Ash[pb][skg + 2][srow][0]);
        gll16(pW + koff,      &Wsh[pb][skg    ][srow][0]);
        gll16(pW + koff + 16, &Wsh[pb][skg + 2][srow][0]);
    };

    stage(0, 0);
    for (int kt = 0; kt < KT; ++kt) {
        const int cur = kt & 1;
        __syncthreads();   // drains vmcnt(0): buf[cur] staged; prev reads done
        if (kt + 1 < KT) stage(kt + 1, cur ^ 1);
        f16x8 a[4], w[4];
        #pragma unroll
        for (int i = 0; i < 4; ++i) {
            a[i] = *(const f16x8*)&Ash[cur][fg][wr + i * 16 + fr][0];
            w[i] = *(const f16x8*)&Wsh[cur][fg][wc + i * 16 + fr][0];
        }
        #pragma unroll
        for (int i = 0; i < 4; ++i)
            #pragma unroll
            for (int j = 0; j < 4; ++j)
                acc[i][j] = __builtin_amdgcn_mfma_f32_16x16x32_f16(a[i], w[j], acc[i][j], 0, 0, 0);
    }
    // C/D layout: col = lane&15, row = (lane>>4)*4 + q
    #pragma unroll
    for (int i = 0; i < 4; ++i) {
        #pragma unroll
        for (int j = 0; j < 4; ++j) {
            int n = bn0 + wc + j * 16 + fr;
            if (n < Nbound) {
                #pragma unroll
                for (int q = 0; q < 4; ++q) {
                    int m = bm0 + wr + i * 16 + fg * 4 + q;
                    float v = acc[i][j][q];
                    if (EPI == 1) {
                        ((unsigned short*)C)[(size_t)m * ldc + n] = f2h(v);
                    } else {
                        if (EPI == 2) v = softplusf(v + bias[n]);
                        C[(size_t)m * ldc + n] = v;
                    }
                }
            }
        }
    }
}

// ---- out[i] = p[i] + p[total+i]  (split-K=2 reduce) ----
__global__ __launch_bounds__(256) void sk2_reduce_kernel(
        const float* __restrict__ p, float* __restrict__ out, int total) {
    int i = blockIdx.x * 256 + threadIdx.x;
    if (i < total) out[i] = p[i] + p[(size_t)total + i];
}

// ---- reduce split-K partials (SKX-way, x_proj) ----
__global__ __launch_bounds__(256) void sk_reduce_kernel(
        const float* __restrict__ part, float* __restrict__ out, int total) {
    int i = blockIdx.x * 256 + threadIdx.x;
    if (i >= total) return;
    float s = 0.f;
    #pragma unroll
    for (int sk = 0; sk < SKX; ++sk) s += part[(size_t)sk * total + i];
    out[i] = s;
}

// ---- depthwise causal conv(4) + bias + SiLU; reads fp16 xz, emits u16 ----
__global__ __launch_bounds__(256) void conv_silu_kernel(
        const unsigned short* __restrict__ xz16, const float* __restrict__ cw,
        const float* __restrict__ cb, unsigned short* __restrict__ u16) {
    int idx = blockIdx.x * 256 + threadIdx.x;
    int d  = idx & (D_INNER - 1);
    int bl = idx >> 11;
    int l  = bl & (SEQLEN - 1);
    const unsigned short* base = xz16 + (size_t)bl * 4096 + d;
    float4 w = *(const float4*)(cw + d * 4);
    float s = cb[d];
    if (l >= 3) s = fmaf(h2f(base[-3 * 4096]), w.x, s);
    if (l >= 2) s = fmaf(h2f(base[-2 * 4096]), w.y, s);
    if (l >= 1) s = fmaf(h2f(base[-1 * 4096]), w.z, s);
    s = fmaf(h2f(base[0]), w.w, s);
    float r = s * __builtin_amdgcn_rcpf(1.f + __expf(-s));
    u16[idx] = f2h(r);
}

// ================= chunk-parallel selective scan (per-thread h[16]) ========
__global__ __launch_bounds__(256) void scan_partA(
        const float* __restrict__ delta, const unsigned short* __restrict__ u16,
        const float* __restrict__ xdbl, const float* __restrict__ A_log,
        float* __restrict__ hF, float* __restrict__ sumd) {
    __shared__ float Bs[TSEG][16];
    const int tid = threadIdx.x;
    const int bx  = blockIdx.x;
    const int seg = bx >> 4;
    const int b   = (bx >> 3) & 1;
    const int d   = (bx & 7) * 256 + tid;
    const int t0  = seg * TSEG;
    {
        const float* bc0 = xdbl + ((size_t)b * SEQLEN + t0) * 96 + 64;
        for (int i = tid; i < TSEG * 16; i += 256)
            Bs[i >> 4][i & 15] = bc0[(size_t)(i >> 4) * 96 + (i & 15)];
    }
    float An2[16];
    #pragma unroll
    for (int q = 0; q < 4; ++q) {
        float4 a = *(const float4*)(A_log + d * 16 + q * 4);
        An2[q*4+0] = -__expf(a.x) * LOG2E;
        An2[q*4+1] = -__expf(a.y) * LOG2E;
        An2[q*4+2] = -__expf(a.z) * LOG2E;
        An2[q*4+3] = -__expf(a.w) * LOG2E;
    }
    const float* dl = delta + ((size_t)b * SEQLEN + t0) * D_INNER + d;
    const unsigned short* uu = u16 + ((size_t)b * SEQLEN + t0) * D_INNER + d;
    float h[16];
    #pragma unroll
    for (int n = 0; n < 16; ++n) h[n] = 0.f;
    float sd = 0.f;
    float pdv[4], puv[4];
    #pragma unroll
    for (int j = 0; j < 4; ++j) {
        pdv[j] = dl[(size_t)j * D_INNER];
        puv[j] = h2f(uu[(size_t)j * D_INNER]);
    }
    __syncthreads();
    for (int t4 = 0; t4 < TSEG; t4 += 4) {
        #pragma unroll
        for (int j = 0; j < 4; ++j) {
            const float dv = pdv[j], uv = puv[j];
            if (t4 + 4 < TSEG) {
                pdv[j] = dl[(size_t)(t4 + 4 + j) * D_INNER];
                puv[j] = h2f(uu[(size_t)(t4 + 4 + j) * D_INNER]);
            }
            const float dvuv = dv * uv;
            sd += dv;
            #pragma unroll
            for (int n = 0; n < 16; ++n)
                h[n] = fmaf(exp2f(dv * An2[n]), h[n], dvuv * Bs[t4 + j][n]);
        }
    }
    const size_t o = (size_t)seg * (BATCH * D_INNER) + (size_t)b * D_INNER + d;
    #pragma unroll
    for (int q = 0; q < 4; ++q)
        *(float4*)(hF + o * 16 + q * 4) =
            make_float4(h[q*4], h[q*4+1], h[q*4+2], h[q*4+3]);
    sumd[o] = sd;
}

// combine over NSEG=64 segments, 4-deep load pipeline (in-place on hF)
__global__ __launch_bounds__(256) void scan_combine(
        const float* __restrict__ A_log, float* hF, const float* __restrict__ sumd) {
    int idx = blockIdx.x * 256 + threadIdx.x;
    int n = idx & 15, row = idx >> 4;
    int d = row & (D_INNER - 1);
    float An = -__expf(A_log[d * 16 + n]);
    float h = 0.f;
    float f[4], sdv[4];
    #pragma unroll
    for (int j = 0; j < 4; ++j) {
        size_t o = (size_t)j * (BATCH * D_INNER) + row;
        f[j]   = hF[o * 16 + n];
        sdv[j] = sumd[o];
    }
    for (int s4 = 0; s4 < NSEG; s4 += 4) {
        float nf[4], nsd[4];
        if (s4 + 4 < NSEG) {
            #pragma unroll
            for (int j = 0; j < 4; ++j) {
                size_t o = (size_t)(s4 + 4 + j) * (BATCH * D_INNER) + row;
                nf[j]  = hF[o * 16 + n];
                nsd[j] = sumd[o];
            }
        }
        #pragma unroll
        for (int j = 0; j < 4; ++j) {
            size_t o = (size_t)(s4 + j) * (BATCH * D_INNER) + row;
            hF[o * 16 + n] = h;
            h = fmaf(__expf(An * sdv[j]), h, f[j]);
        }
        #pragma unroll
        for (int j = 0; j < 4; ++j) { f[j] = nf[j]; sdv[j] = nsd[j]; }
    }
}

// partB: re-scan from hin, emit y*silu(z). yg aliases delta; z from fp16 xz.
__global__ __launch_bounds__(256) void scan_partB(
        const float* delta, const unsigned short* __restrict__ u16,
        const float* __restrict__ xdbl, const unsigned short* __restrict__ xz16,
        const float* __restrict__ A_log, const float* __restrict__ Dp,
        const float* __restrict__ hin, float* yg) {
    __shared__ float BCs[TSEG][32];
    const int tid = threadIdx.x;
    const int bx  = blockIdx.x;
    const int seg = bx >> 4;
    const int b   = (bx >> 3) & 1;
    const int d   = (bx & 7) * 256 + tid;
    const int t0  = seg * TSEG;
    {
        const float* bc0 = xdbl + ((size_t)b * SEQLEN + t0) * 96 + 64;
        for (int i = tid; i < TSEG * 32; i += 256)
            BCs[i >> 5][i & 31] = bc0[(size_t)(i >> 5) * 96 + (i & 31)];
    }
    float An2[16];
    #pragma unroll
    for (int q = 0; q < 4; ++q) {
        float4 a = *(const float4*)(A_log + d * 16 + q * 4);
        An2[q*4+0] = -__expf(a.x) * LOG2E;
        An2[q*4+1] = -__expf(a.y) * LOG2E;
        An2[q*4+2] = -__expf(a.z) * LOG2E;
        An2[q*4+3] = -__expf(a.w) * LOG2E;
    }
    const float Dd = Dp[d];
    const float* dl = delta + ((size_t)b * SEQLEN + t0) * D_INNER + d;
    const unsigned short* uu = u16 + ((size_t)b * SEQLEN + t0) * D_INNER + d;
    const unsigned short* zz = xz16 + ((size_t)b * SEQLEN + t0) * 4096 + D_INNER + d;
    float* yo = yg + ((size_t)b * SEQLEN + t0) * D_INNER + d;
    const size_t o = (size_t)seg * (BATCH * D_INNER) + (size_t)b * D_INNER + d;
    float h[16];
    #pragma unroll
    for (int q = 0; q < 4; ++q) {
        float4 hv = *(const float4*)(hin + o * 16 + q * 4);
        h[q*4] = hv.x; h[q*4+1] = hv.y; h[q*4+2] = hv.z; h[q*4+3] = hv.w;
    }
    float pdv[4], puv[4], pzv[4];
    #pragma unroll
    for (int j = 0; j < 4; ++j) {
        pdv[j] = dl[(size_t)j * D_INNER];
        puv[j] = h2f(uu[(size_t)j * D_INNER]);
        pzv[j] = h2f(zz[(size_t)j * 4096]);
    }
    __syncthreads();
    for (int t4 = 0; t4 < TSEG; t4 += 4) {
        #pragma unroll
        for (int j = 0; j < 4; ++j) {
            const float dv = pdv[j], uv = puv[j], zv = pzv[j];
            if (t4 + 4 < TSEG) {
                pdv[j] = dl[(size_t)(t4 + 4 + j) * D_INNER];
                puv[j] = h2f(uu[(size_t)(t4 + 4 + j) * D_INNER]);
                pzv[j] = h2f(zz[(size_t)(t4 + 4 + j) * 4096]);
            }
            const float dvuv = dv * uv;
            #pragma unroll
            for (int n = 0; n < 16; ++n)
                h[n] = fmaf(exp2f(dv * An2[n]), h[n], dvuv * BCs[t4 + j][n]);
            float acc[4] = {0.f, 0.f, 0.f, 0.f};
            #pragma unroll
            for (int n = 0; n < 16; ++n)
                acc[n & 3] = fmaf(h[n], BCs[t4 + j][16 + n], acc[n & 3]);
            float yv = fmaf(uv, Dd, (acc[0] + acc[1]) + (acc[2] + acc[3]));
            float sig = zv * __builtin_amdgcn_rcpf(1.f + __expf(-zv));
            yo[(size_t)(t4 + j) * D_INNER] = yv * sig;
        }
    }
}

extern "C" void kernel_launch(void* const* d_in, const int* in_sizes, int n_in,
                              void* d_out, int out_size, void* d_ws, size_t ws_size,
                              hipStream_t stream) {
    const float* x        = (const float*)d_in[0];
    const float* w_in     = (const float*)d_in[1];
    const float* lA_in    = (const float*)d_in[2];
    const float* lB_in    = (const float*)d_in[3];
    const float* mask_in  = (const float*)d_in[4];
    const float* conv_w   = (const float*)d_in[5];
    const float* conv_b   = (const float*)d_in[6];
    const float* w_xp     = (const float*)d_in[7];
    const float* w_dt     = (const float*)d_in[8];
    const float* b_dt     = (const float*)d_in[9];
    const float* A_log    = (const float*)d_in[10];
    const float* Dp       = (const float*)d_in[11];
    const float* w_out    = (const float*)d_in[12];
    const float* lA_out   = (const float*)d_in[13];
    const float* lB_out   = (const float*)d_in[14];
    const float* mask_out = (const float*)d_in[15];

    // f32 workspace layout
    float* ws    = (float*)d_ws;
    float* xz    = ws;                              // [BL,4096] region (fp16 xz + hF/sumd)
    float* u     = xz    + (size_t)BL * 4096;       // [BL,2048] (A16/W16_in, then u16)
    float* delta = u     + (size_t)BL * D_INNER;    // [BL,2048] (delta/yg; out partials)
    float* xdbl  = delta + (size_t)BL * D_INNER;    // [BL,96]

    // xz region internals: fp16 xz (33.5 MB) + contiguous hF/sumd (17.8 MB)
    unsigned short* xz16 = (unsigned short*)xz;                  // [BL][4096]
    float* hF   = xz + (size_t)BL * 2048;                        // [NSEG*BL][16]
    float* sumd = hF + (size_t)NSEG * BATCH * D_INNER * 16;      // [NSEG*BL]

    // fp16 arenas for in_proj in u region; KP_IN=1056
    const int KP_IN = 1056;
    unsigned short* A16_in = (unsigned short*)u;                 // [4096][1056]
    unsigned short* W16_in = A16_in + (size_t)4096 * KP_IN;      // [4096][1056]
    unsigned short* u16 = (unsigned short*)u;                    // [4096][2048] (after in_proj)

    // fp16 arenas for out_proj overwrite xz16 (dead after partB); KP=2112
    const int KP_OUT = 2112, KH_OUT = 1056;
    unsigned short* A16_out = (unsigned short*)xz;               // [4096][2112]
    unsigned short* W16_out = A16_out + (size_t)4096 * KP_OUT;   // [1024][2112]

    // d_out f32 scratch (pre-final uses)
    float* outf    = (float*)d_out;
    float* xp_part = outf;                                   // [SKX][BL*96] = 12.6MB
    unsigned short* W16_xp = (unsigned short*)(outf + (size_t)SKX * BL * 96); // [128][2048]
    unsigned short* A16_dt = (unsigned short*)d_out;             // [4096][64] (after xp consumed)
    unsigned short* W16_dt = A16_dt + (size_t)4096 * 64;         // [2048][64]

    // 1) fused x conversion + LoRA-A dot + ext cols
    fused_x16_kernel<<<4096, 256, 0, stream>>>(x, lA_in, A16_in);
    // 2) fused w_in conversion + LoRA-B ext cols
    cvt16w_ext_kernel<<<4096, 256, 0, stream>>>(w_in, lB_in, mask_in, 1024, KP_IN, 32, W16_in);
    // 3) in_proj fp16 MFMA GEMM (256^2 tile) -> xz16 (fp16 output)
    mfma_gemm16_256<<<dim3(16, 16), 512, 0, stream>>>(
        A16_in, W16_in, KP_IN, xz16, 4096);
    // 4) u16 = fp16(silu(conv(xs16) + b))  (overwrites A16_in arena — dead)
    conv_silu_kernel<<<(BL * D_INNER) / 256, 256, 0, stream>>>(xz16, conv_w, conv_b, u16);
    // 5) x_proj fp16 MFMA split-K=8 -> partials (d_out) -> xdbl
    cvtpad16_kernel<<<(128 * 512 + 255) / 256, 256, 0, stream>>>(w_xp, 96, 512, W16_xp, 128 * 512);
    mfma_gemm16<0><<<dim3(1, 32, SKX), 256, 0, stream>>>(
        u16, W16_xp, 2048, xp_part, 96, nullptr, 96, KCH);
    sk_reduce_kernel<<<(BL * 96 + 255) / 256, 256, 0, stream>>>(xp_part, xdbl, BL * 96);
    // 6) dt_proj: fused conversions, then fp16 MFMA (K=64) -> delta = softplus
    cvt16dt_kernel<<<(4096 * 16 + 2048 * 16 + 255) / 256, 256, 0, stream>>>(
        xdbl, w_dt, A16_dt, W16_dt);
    mfma_gemm16<2><<<dim3(16, 32), 256, 0, stream>>>(
        A16_dt, W16_dt, 64, delta, 2048, b_dt, 2048, 0);
    // 7) chunk-parallel selective scan (+ gating)
    scan_partA<<<NSEG * BATCH * 8, 256, 0, stream>>>(delta, u16, xdbl, A_log, hF, sumd);
    scan_combine<<<(BATCH * D_INNER * 16) / 256, 256, 0, stream>>>(A_log, hF, sumd);
    scan_partB<<<NSEG * BATCH * 8, 256, 0, stream>>>(delta, u16, xdbl, xz16, A_log, Dp, hF, delta);
    // 8) out_proj: fused A16_out (+ext) from y; fused W16_out (+ext)
    fused_y16_kernel<<<BL, 256, 0, stream>>>(delta, lA_out, A16_out, KP_OUT);
    cvt16w_ext_kernel<<<1024, 256, 0, stream>>>(w_out, lB_out, mask_out, 2048, KP_OUT, 64, W16_out);
    // 9) out_proj fp16 split-K=2 -> partials in dead delta region, then reduce
    float* P = delta;   // y consumed by fused_y16
    mfma_gemm16<0><<<dim3(8, 32, 2), 256, 0, stream>>>(
        A16_out, W16_out, KP_OUT, P, 1024, nullptr, 1024, KH_OUT);
    sk2_reduce_kernel<<<(4096 * 1024) / 256, 256, 0, stream>>>(P, (float*)d_out, 4096 * 1024);
}

// Round 18
// 377.067 us; speedup vs baseline: 1.0357x; 1.0357x over previous
//
#include <hip/hip_runtime.h>
#include <hip/hip_bf16.h>
#include <hip/hip_fp16.h>
#include <cstdint>
#include <cstddef>

// Problem constants (from reference)
#define D_MODEL 1024
#define D_INNER 2048
#define NSTATE  16
#define DTRANK  64
#define BATCH   2
#define SEQLEN  2048
#define BL      (BATCH*SEQLEN)   // 4096 tokens
#define NSEG    64
#define TSEG    (SEQLEN/NSEG)    // 32
#define SKX     8                // split-K factor for x_proj
#define KCH     (D_INNER/SKX)    // 256
#define LOG2E   1.4426950408889634f

typedef __attribute__((ext_vector_type(8))) _Float16 f16x8;
typedef __attribute__((ext_vector_type(4))) float f32x4;

__device__ __forceinline__ float softplusf(float x) {
    return fmaxf(x, 0.f) + log1pf(expf(-fabsf(x)));
}
__device__ __forceinline__ unsigned short f2h(float x) {
    __half h = __float2half(x);
    return *(unsigned short*)&h;
}
__device__ __forceinline__ float h2f(unsigned short u) {
    __half h; *(unsigned short*)&h = u;
    return __half2float(h);
}
// async global->LDS, 16B per lane (dest must be linear: base + lane*16)
__device__ __forceinline__ void gll16(const void* g, void* l) {
    __builtin_amdgcn_global_load_lds(
        (const __attribute__((address_space(1))) void*)g,
        (__attribute__((address_space(3))) void*)l, 16, 0, 0);
}

// ---- fused: A16 row m = fp16(x row); LoRA dot -> ext cols [1024,1056) ----
__global__ __launch_bounds__(256) void fused_x16_kernel(
        const float* __restrict__ x, const float* __restrict__ lA,
        unsigned short* __restrict__ A16) {
    const int m = blockIdx.x, tid = threadIdx.x;
    float4 v = *(const float4*)(x + (size_t)m * 1024 + tid * 4);
    ushort4 hv = {f2h(v.x), f2h(v.y), f2h(v.z), f2h(v.w)};
    *(ushort4*)(A16 + (size_t)m * 1056 + tid * 4) = hv;
    float p[16];
    #pragma unroll
    for (int r = 0; r < 16; ++r) {
        float4 a = *(const float4*)(lA + (size_t)r * 1024 + tid * 4);
        p[r] = v.x * a.x + v.y * a.y + v.z * a.z + v.w * a.w;
    }
    #pragma unroll
    for (int r = 0; r < 16; ++r)
        #pragma unroll
        for (int o = 32; o; o >>= 1) p[r] += __shfl_xor(p[r], o);
    __shared__ float red[4][16];
    const int lane = tid & 63, wv = tid >> 6;
    if (lane == 0) {
        #pragma unroll
        for (int r = 0; r < 16; ++r) red[wv][r] = p[r];
    }
    __syncthreads();
    if (tid < 32) {
        float val = 0.f;
        if (tid < 16)
            val = (red[0][tid] + red[1][tid]) + (red[2][tid] + red[3][tid]);
        A16[(size_t)m * 1056 + 1024 + tid] = f2h(val);
    }
}

// ---- fused: W16 row n = fp16(w row); ext cols = lb[n][c]*mask[n]*2 ----
__global__ __launch_bounds__(256) void cvt16w_ext_kernel(
        const float* __restrict__ w, const float* __restrict__ lb,
        const float* __restrict__ mask, int K, int KP, int ncols,
        unsigned short* __restrict__ dst) {
    const int n = blockIdx.x, tid = threadIdx.x;
    for (int k = tid * 4; k < K; k += 1024) {
        float4 v = *(const float4*)(w + (size_t)n * K + k);
        ushort4 h = {f2h(v.x), f2h(v.y), f2h(v.z), f2h(v.w)};
        *(ushort4*)(dst + (size_t)n * KP + k) = h;
    }
    if (tid < ncols) {
        float val = (tid < 16) ? lb[(size_t)n * 16 + tid] * mask[n] * 2.0f : 0.f;
        dst[(size_t)n * KP + K + tid] = f2h(val);
    }
}

// ---- fused: A16_out row = fp16(y row); LoRA dot -> ext cols [2048,2112) ----
__global__ __launch_bounds__(256) void fused_y16_kernel(
        const float* __restrict__ y, const float* __restrict__ lA,
        unsigned short* __restrict__ A16, int KP) {
    const int m = blockIdx.x, tid = threadIdx.x;
    const float* yr = y + (size_t)m * 2048;
    float4 v0 = *(const float4*)(yr + tid * 8);
    float4 v1 = *(const float4*)(yr + tid * 8 + 4);
    float yv[8] = {v0.x, v0.y, v0.z, v0.w, v1.x, v1.y, v1.z, v1.w};
    ushort4 h0 = {f2h(yv[0]), f2h(yv[1]), f2h(yv[2]), f2h(yv[3])};
    ushort4 h1 = {f2h(yv[4]), f2h(yv[5]), f2h(yv[6]), f2h(yv[7])};
    *(ushort4*)(A16 + (size_t)m * KP + tid * 8)     = h0;
    *(ushort4*)(A16 + (size_t)m * KP + tid * 8 + 4) = h1;
    float p[16];
    #pragma unroll
    for (int r = 0; r < 16; ++r) {
        const float* lr = lA + (size_t)r * 2048 + tid * 8;
        float4 a0 = *(const float4*)lr;
        float4 a1 = *(const float4*)(lr + 4);
        p[r] = yv[0]*a0.x + yv[1]*a0.y + yv[2]*a0.z + yv[3]*a0.w
             + yv[4]*a1.x + yv[5]*a1.y + yv[6]*a1.z + yv[7]*a1.w;
    }
    #pragma unroll
    for (int r = 0; r < 16; ++r)
        #pragma unroll
        for (int o = 32; o; o >>= 1) p[r] += __shfl_xor(p[r], o);
    __shared__ float red[4][16];
    const int lane = tid & 63, wv = tid >> 6;
    if (lane == 0) {
        #pragma unroll
        for (int r = 0; r < 16; ++r) red[wv][r] = p[r];
    }
    __syncthreads();
    if (tid < 64) {
        float val = 0.f;
        if (tid < 16)
            val = (red[0][tid] + red[1][tid]) + (red[2][tid] + red[3][tid]);
        A16[(size_t)m * KP + 2048 + tid] = f2h(val);
    }
}

// ---- fp16 convert with row padding: rows >= Msrc write zeros ----
__global__ __launch_bounds__(256) void cvtpad16_kernel(
        const float* __restrict__ src, int Msrc, int K4,
        unsigned short* __restrict__ dst, int total4) {
    int idx = blockIdx.x * 256 + threadIdx.x;
    if (idx >= total4) return;
    int m = idx / K4;
    int kq = idx - m * K4;
    ushort4 h = {0, 0, 0, 0};
    if (m < Msrc) {
        float4 v = *(const float4*)(src + (size_t)m * (K4 * 4) + kq * 4);
        h.x = f2h(v.x); h.y = f2h(v.y); h.z = f2h(v.z); h.w = f2h(v.w);
    }
    *(ushort4*)(dst + (size_t)m * (K4 * 4) + kq * 4) = h;
}

// ---- fused dt conversions: A16_dt from xdbl[:, :64], W16_dt from w_dt ----
__global__ __launch_bounds__(256) void cvt16dt_kernel(
        const float* __restrict__ xdbl, const float* __restrict__ w_dt,
        unsigned short* __restrict__ A16, unsigned short* __restrict__ W16) {
    int idx = blockIdx.x * 256 + threadIdx.x;
    if (idx < 4096 * 16) {
        int m = idx >> 4, kq = idx & 15;
        float4 v = *(const float4*)(xdbl + (size_t)m * 96 + kq * 4);
        ushort4 h = {f2h(v.x), f2h(v.y), f2h(v.z), f2h(v.w)};
        *(ushort4*)(A16 + (size_t)m * 64 + kq * 4) = h;
    } else {
        int j = idx - 4096 * 16;
        if (j >= 2048 * 16) return;
        int m = j >> 4, kq = j & 15;
        float4 v = *(const float4*)(w_dt + (size_t)m * 64 + kq * 4);
        ushort4 h = {f2h(v.x), f2h(v.y), f2h(v.z), f2h(v.w)};
        *(ushort4*)(W16 + (size_t)m * 64 + kq * 4) = h;
    }
}

// ---- fp16 single-pass MFMA GEMM, BK=32, 2-phase dbuf, split-K + N bound ----
// EPI==0: f32 store. EPI==1: fp16 store. EPI==2: softplus(v+bias[n]) f32.
template<int EPI>
__global__ __launch_bounds__(256, 4) void mfma_gemm16(
        const unsigned short* __restrict__ Ag, const unsigned short* __restrict__ Wg,
        int KP, float* __restrict__ C, int ldc,
        const float* __restrict__ bias, int Nbound, int kchunk) {
    __shared__ __align__(16) short Ash[2][4][128][8];
    __shared__ __align__(16) short Wsh[2][4][128][8];
    const int tid = threadIdx.x;
    const int bn0 = blockIdx.x * 128, bm0 = blockIdx.y * 128;
    const int wave = tid >> 6, lane = tid & 63;
    const int wr = (wave >> 1) * 64, wc = (wave & 1) * 64;
    const int fr = lane & 15, fg = lane >> 4;
    int koff0 = 0, KT;
    if (kchunk) {
        koff0 = blockIdx.z * kchunk;
        KT = kchunk >> 5;
        C += (size_t)blockIdx.z * gridDim.y * 128 * ldc;
    } else {
        KT = KP >> 5;
    }
    const int srow = tid & 127, skg = tid >> 7;

    const unsigned short* pA = Ag + (size_t)(bm0 + srow) * KP + koff0 + skg * 8;
    const unsigned short* pW = Wg + (size_t)(bn0 + srow) * KP + koff0 + skg * 8;

    f32x4 acc[4][4];
    #pragma unroll
    for (int i = 0; i < 4; ++i)
        #pragma unroll
        for (int j = 0; j < 4; ++j) acc[i][j] = (f32x4){0.f, 0.f, 0.f, 0.f};

    auto stage = [&](int kt, int pb) {
        const int koff = kt * 32;
        gll16(pA + koff,      &Ash[pb][skg    ][srow][0]);
        gll16(pA + koff + 16, &Ash[pb][skg + 2][srow][0]);
        gll16(pW + koff,      &Wsh[pb][skg    ][srow][0]);
        gll16(pW + koff + 16, &Wsh[pb][skg + 2][srow][0]);
    };

    stage(0, 0);
    for (int kt = 0; kt < KT; ++kt) {
        const int cur = kt & 1;
        __syncthreads();   // drains vmcnt(0): buf[cur] staged; prev reads done
        if (kt + 1 < KT) stage(kt + 1, cur ^ 1);
        f16x8 a[4], w[4];
        #pragma unroll
        for (int i = 0; i < 4; ++i) {
            a[i] = *(const f16x8*)&Ash[cur][fg][wr + i * 16 + fr][0];
            w[i] = *(const f16x8*)&Wsh[cur][fg][wc + i * 16 + fr][0];
        }
        #pragma unroll
        for (int i = 0; i < 4; ++i)
            #pragma unroll
            for (int j = 0; j < 4; ++j)
                acc[i][j] = __builtin_amdgcn_mfma_f32_16x16x32_f16(a[i], w[j], acc[i][j], 0, 0, 0);
    }
    // C/D layout: col = lane&15, row = (lane>>4)*4 + q
    #pragma unroll
    for (int i = 0; i < 4; ++i) {
        #pragma unroll
        for (int j = 0; j < 4; ++j) {
            int n = bn0 + wc + j * 16 + fr;
            if (n < Nbound) {
                #pragma unroll
                for (int q = 0; q < 4; ++q) {
                    int m = bm0 + wr + i * 16 + fg * 4 + q;
                    float v = acc[i][j][q];
                    if (EPI == 1) {
                        ((unsigned short*)C)[(size_t)m * ldc + n] = f2h(v);
                    } else {
                        if (EPI == 2) v = softplusf(v + bias[n]);
                        C[(size_t)m * ldc + n] = v;
                    }
                }
            }
        }
    }
}

// ---- out[i] = p[i] + p[total+i]  (split-K=2 reduce) ----
__global__ __launch_bounds__(256) void sk2_reduce_kernel(
        const float* __restrict__ p, float* __restrict__ out, int total) {
    int i = blockIdx.x * 256 + threadIdx.x;
    if (i < total) out[i] = p[i] + p[(size_t)total + i];
}

// ---- reduce split-K partials (SKX-way, x_proj) ----
__global__ __launch_bounds__(256) void sk_reduce_kernel(
        const float* __restrict__ part, float* __restrict__ out, int total) {
    int i = blockIdx.x * 256 + threadIdx.x;
    if (i >= total) return;
    float s = 0.f;
    #pragma unroll
    for (int sk = 0; sk < SKX; ++sk) s += part[(size_t)sk * total + i];
    out[i] = s;
}

// ---- depthwise causal conv(4) + bias + SiLU; reads fp16 xz, emits u16 ----
__global__ __launch_bounds__(256) void conv_silu_kernel(
        const unsigned short* __restrict__ xz16, const float* __restrict__ cw,
        const float* __restrict__ cb, unsigned short* __restrict__ u16) {
    int idx = blockIdx.x * 256 + threadIdx.x;
    int d  = idx & (D_INNER - 1);
    int bl = idx >> 11;
    int l  = bl & (SEQLEN - 1);
    const unsigned short* base = xz16 + (size_t)bl * 4096 + d;
    float4 w = *(const float4*)(cw + d * 4);
    float s = cb[d];
    if (l >= 3) s = fmaf(h2f(base[-3 * 4096]), w.x, s);
    if (l >= 2) s = fmaf(h2f(base[-2 * 4096]), w.y, s);
    if (l >= 1) s = fmaf(h2f(base[-1 * 4096]), w.z, s);
    s = fmaf(h2f(base[0]), w.w, s);
    float r = s * __builtin_amdgcn_rcpf(1.f + __expf(-s));
    u16[idx] = f2h(r);
}

// ================= chunk-parallel selective scan (per-thread h[16]) ========
__global__ __launch_bounds__(256) void scan_partA(
        const float* __restrict__ delta, const unsigned short* __restrict__ u16,
        const float* __restrict__ xdbl, const float* __restrict__ A_log,
        float* __restrict__ hF, float* __restrict__ sumd) {
    __shared__ float Bs[TSEG][16];
    const int tid = threadIdx.x;
    const int bx  = blockIdx.x;
    const int seg = bx >> 4;
    const int b   = (bx >> 3) & 1;
    const int d   = (bx & 7) * 256 + tid;
    const int t0  = seg * TSEG;
    {
        const float* bc0 = xdbl + ((size_t)b * SEQLEN + t0) * 96 + 64;
        for (int i = tid; i < TSEG * 16; i += 256)
            Bs[i >> 4][i & 15] = bc0[(size_t)(i >> 4) * 96 + (i & 15)];
    }
    float An2[16];
    #pragma unroll
    for (int q = 0; q < 4; ++q) {
        float4 a = *(const float4*)(A_log + d * 16 + q * 4);
        An2[q*4+0] = -__expf(a.x) * LOG2E;
        An2[q*4+1] = -__expf(a.y) * LOG2E;
        An2[q*4+2] = -__expf(a.z) * LOG2E;
        An2[q*4+3] = -__expf(a.w) * LOG2E;
    }
    const float* dl = delta + ((size_t)b * SEQLEN + t0) * D_INNER + d;
    const unsigned short* uu = u16 + ((size_t)b * SEQLEN + t0) * D_INNER + d;
    float h[16];
    #pragma unroll
    for (int n = 0; n < 16; ++n) h[n] = 0.f;
    float sd = 0.f;
    float pdv[4], puv[4];
    #pragma unroll
    for (int j = 0; j < 4; ++j) {
        pdv[j] = dl[(size_t)j * D_INNER];
        puv[j] = h2f(uu[(size_t)j * D_INNER]);
    }
    __syncthreads();
    for (int t4 = 0; t4 < TSEG; t4 += 4) {
        #pragma unroll
        for (int j = 0; j < 4; ++j) {
            const float dv = pdv[j], uv = puv[j];
            if (t4 + 4 < TSEG) {
                pdv[j] = dl[(size_t)(t4 + 4 + j) * D_INNER];
                puv[j] = h2f(uu[(size_t)(t4 + 4 + j) * D_INNER]);
            }
            const float dvuv = dv * uv;
            sd += dv;
            #pragma unroll
            for (int n = 0; n < 16; ++n)
                h[n] = fmaf(exp2f(dv * An2[n]), h[n], dvuv * Bs[t4 + j][n]);
        }
    }
    const size_t o = (size_t)seg * (BATCH * D_INNER) + (size_t)b * D_INNER + d;
    #pragma unroll
    for (int q = 0; q < 4; ++q)
        *(float4*)(hF + o * 16 + q * 4) =
            make_float4(h[q*4], h[q*4+1], h[q*4+2], h[q*4+3]);
    sumd[o] = sd;
}

// combine over NSEG=64 segments, 4-deep load pipeline (in-place on hF)
__global__ __launch_bounds__(256) void scan_combine(
        const float* __restrict__ A_log, float* hF, const float* __restrict__ sumd) {
    int idx = blockIdx.x * 256 + threadIdx.x;
    int n = idx & 15, row = idx >> 4;
    int d = row & (D_INNER - 1);
    float An = -__expf(A_log[d * 16 + n]);
    float h = 0.f;
    float f[4], sdv[4];
    #pragma unroll
    for (int j = 0; j < 4; ++j) {
        size_t o = (size_t)j * (BATCH * D_INNER) + row;
        f[j]   = hF[o * 16 + n];
        sdv[j] = sumd[o];
    }
    for (int s4 = 0; s4 < NSEG; s4 += 4) {
        float nf[4], nsd[4];
        if (s4 + 4 < NSEG) {
            #pragma unroll
            for (int j = 0; j < 4; ++j) {
                size_t o = (size_t)(s4 + 4 + j) * (BATCH * D_INNER) + row;
                nf[j]  = hF[o * 16 + n];
                nsd[j] = sumd[o];
            }
        }
        #pragma unroll
        for (int j = 0; j < 4; ++j) {
            size_t o = (size_t)(s4 + j) * (BATCH * D_INNER) + row;
            hF[o * 16 + n] = h;
            h = fmaf(__expf(An * sdv[j]), h, f[j]);
        }
        #pragma unroll
        for (int j = 0; j < 4; ++j) { f[j] = nf[j]; sdv[j] = nsd[j]; }
    }
}

// partB: re-scan from hin, emit y*silu(z). yg aliases delta; z from fp16 xz.
__global__ __launch_bounds__(256) void scan_partB(
        const float* delta, const unsigned short* __restrict__ u16,
        const float* __restrict__ xdbl, const unsigned short* __restrict__ xz16,
        const float* __restrict__ A_log, const float* __restrict__ Dp,
        const float* __restrict__ hin, float* yg) {
    __shared__ float BCs[TSEG][32];
    const int tid = threadIdx.x;
    const int bx  = blockIdx.x;
    const int seg = bx >> 4;
    const int b   = (bx >> 3) & 1;
    const int d   = (bx & 7) * 256 + tid;
    const int t0  = seg * TSEG;
    {
        const float* bc0 = xdbl + ((size_t)b * SEQLEN + t0) * 96 + 64;
        for (int i = tid; i < TSEG * 32; i += 256)
            BCs[i >> 5][i & 31] = bc0[(size_t)(i >> 5) * 96 + (i & 31)];
    }
    float An2[16];
    #pragma unroll
    for (int q = 0; q < 4; ++q) {
        float4 a = *(const float4*)(A_log + d * 16 + q * 4);
        An2[q*4+0] = -__expf(a.x) * LOG2E;
        An2[q*4+1] = -__expf(a.y) * LOG2E;
        An2[q*4+2] = -__expf(a.z) * LOG2E;
        An2[q*4+3] = -__expf(a.w) * LOG2E;
    }
    const float Dd = Dp[d];
    const float* dl = delta + ((size_t)b * SEQLEN + t0) * D_INNER + d;
    const unsigned short* uu = u16 + ((size_t)b * SEQLEN + t0) * D_INNER + d;
    const unsigned short* zz = xz16 + ((size_t)b * SEQLEN + t0) * 4096 + D_INNER + d;
    float* yo = yg + ((size_t)b * SEQLEN + t0) * D_INNER + d;
    const size_t o = (size_t)seg * (BATCH * D_INNER) + (size_t)b * D_INNER + d;
    float h[16];
    #pragma unroll
    for (int q = 0; q < 4; ++q) {
        float4 hv = *(const float4*)(hin + o * 16 + q * 4);
        h[q*4] = hv.x; h[q*4+1] = hv.y; h[q*4+2] = hv.z; h[q*4+3] = hv.w;
    }
    float pdv[4], puv[4], pzv[4];
    #pragma unroll
    for (int j = 0; j < 4; ++j) {
        pdv[j] = dl[(size_t)j * D_INNER];
        puv[j] = h2f(uu[(size_t)j * D_INNER]);
        pzv[j] = h2f(zz[(size_t)j * 4096]);
    }
    __syncthreads();
    for (int t4 = 0; t4 < TSEG; t4 += 4) {
        #pragma unroll
        for (int j = 0; j < 4; ++j) {
            const float dv = pdv[j], uv = puv[j], zv = pzv[j];
            if (t4 + 4 < TSEG) {
                pdv[j] = dl[(size_t)(t4 + 4 + j) * D_INNER];
                puv[j] = h2f(uu[(size_t)(t4 + 4 + j) * D_INNER]);
                pzv[j] = h2f(zz[(size_t)(t4 + 4 + j) * 4096]);
            }
            const float dvuv = dv * uv;
            #pragma unroll
            for (int n = 0; n < 16; ++n)
                h[n] = fmaf(exp2f(dv * An2[n]), h[n], dvuv * BCs[t4 + j][n]);
            float acc[4] = {0.f, 0.f, 0.f, 0.f};
            #pragma unroll
            for (int n = 0; n < 16; ++n)
                acc[n & 3] = fmaf(h[n], BCs[t4 + j][16 + n], acc[n & 3]);
            float yv = fmaf(uv, Dd, (acc[0] + acc[1]) + (acc[2] + acc[3]));
            float sig = zv * __builtin_amdgcn_rcpf(1.f + __expf(-zv));
            yo[(size_t)(t4 + j) * D_INNER] = yv * sig;
        }
    }
}

extern "C" void kernel_launch(void* const* d_in, const int* in_sizes, int n_in,
                              void* d_out, int out_size, void* d_ws, size_t ws_size,
                              hipStream_t stream) {
    const float* x        = (const float*)d_in[0];
    const float* w_in     = (const float*)d_in[1];
    const float* lA_in    = (const float*)d_in[2];
    const float* lB_in    = (const float*)d_in[3];
    const float* mask_in  = (const float*)d_in[4];
    const float* conv_w   = (const float*)d_in[5];
    const float* conv_b   = (const float*)d_in[6];
    const float* w_xp     = (const float*)d_in[7];
    const float* w_dt     = (const float*)d_in[8];
    const float* b_dt     = (const float*)d_in[9];
    const float* A_log    = (const float*)d_in[10];
    const float* Dp       = (const float*)d_in[11];
    const float* w_out    = (const float*)d_in[12];
    const float* lA_out   = (const float*)d_in[13];
    const float* lB_out   = (const float*)d_in[14];
    const float* mask_out = (const float*)d_in[15];

    // f32 workspace layout
    float* ws    = (float*)d_ws;
    float* xz    = ws;                              // [BL,4096] region (fp16 xz + hF/sumd)
    float* u     = xz    + (size_t)BL * 4096;       // [BL,2048] (A16/W16_in, then u16)
    float* delta = u     + (size_t)BL * D_INNER;    // [BL,2048] (delta/yg; out partials)
    float* xdbl  = delta + (size_t)BL * D_INNER;    // [BL,96]

    // xz region internals: fp16 xz (33.5 MB) + contiguous hF/sumd (17.8 MB)
    unsigned short* xz16 = (unsigned short*)xz;                  // [BL][4096]
    float* hF   = xz + (size_t)BL * 2048;                        // [NSEG*BL][16]
    float* sumd = hF + (size_t)NSEG * BATCH * D_INNER * 16;      // [NSEG*BL]

    // fp16 arenas for in_proj in u region; KP_IN=1056
    const int KP_IN = 1056;
    unsigned short* A16_in = (unsigned short*)u;                 // [4096][1056]
    unsigned short* W16_in = A16_in + (size_t)4096 * KP_IN;      // [4096][1056]
    unsigned short* u16 = (unsigned short*)u;                    // [4096][2048] (after in_proj)

    // fp16 arenas for out_proj overwrite xz16 (dead after partB); KP=2112
    const int KP_OUT = 2112, KH_OUT = 1056;
    unsigned short* A16_out = (unsigned short*)xz;               // [4096][2112]
    unsigned short* W16_out = A16_out + (size_t)4096 * KP_OUT;   // [1024][2112]

    // d_out f32 scratch (pre-final uses)
    float* outf    = (float*)d_out;
    float* xp_part = outf;                                   // [SKX][BL*96] = 12.6MB
    unsigned short* W16_xp = (unsigned short*)(outf + (size_t)SKX * BL * 96); // [128][2048]
    unsigned short* A16_dt = (unsigned short*)d_out;             // [4096][64] (after xp consumed)
    unsigned short* W16_dt = A16_dt + (size_t)4096 * 64;         // [2048][64]

    // 1) fused x conversion + LoRA-A dot + ext cols
    fused_x16_kernel<<<4096, 256, 0, stream>>>(x, lA_in, A16_in);
    // 2) fused w_in conversion + LoRA-B ext cols
    cvt16w_ext_kernel<<<4096, 256, 0, stream>>>(w_in, lB_in, mask_in, 1024, KP_IN, 32, W16_in);
    // 3) in_proj fp16 MFMA GEMM -> xz16 (fp16 output)
    mfma_gemm16<1><<<dim3(32, 32), 256, 0, stream>>>(
        A16_in, W16_in, KP_IN, (float*)xz16, 4096, nullptr, 4096, 0);
    // 4) u16 = fp16(silu(conv(xs16) + b))  (overwrites A16_in arena — dead)
    conv_silu_kernel<<<(BL * D_INNER) / 256, 256, 0, stream>>>(xz16, conv_w, conv_b, u16);
    // 5) x_proj fp16 MFMA split-K=8 -> partials (d_out) -> xdbl
    cvtpad16_kernel<<<(128 * 512 + 255) / 256, 256, 0, stream>>>(w_xp, 96, 512, W16_xp, 128 * 512);
    mfma_gemm16<0><<<dim3(1, 32, SKX), 256, 0, stream>>>(
        u16, W16_xp, 2048, xp_part, 96, nullptr, 96, KCH);
    sk_reduce_kernel<<<(BL * 96 + 255) / 256, 256, 0, stream>>>(xp_part, xdbl, BL * 96);
    // 6) dt_proj: fused conversions, then fp16 MFMA (K=64) -> delta = softplus
    cvt16dt_kernel<<<(4096 * 16 + 2048 * 16 + 255) / 256, 256, 0, stream>>>(
        xdbl, w_dt, A16_dt, W16_dt);
    mfma_gemm16<2><<<dim3(16, 32), 256, 0, stream>>>(
        A16_dt, W16_dt, 64, delta, 2048, b_dt, 2048, 0);
    // 7) chunk-parallel selective scan (+ gating)
    scan_partA<<<NSEG * BATCH * 8, 256, 0, stream>>>(delta, u16, xdbl, A_log, hF, sumd);
    scan_combine<<<(BATCH * D_INNER * 16) / 256, 256, 0, stream>>>(A_log, hF, sumd);
    scan_partB<<<NSEG * BATCH * 8, 256, 0, stream>>>(delta, u16, xdbl, xz16, A_log, Dp, hF, delta);
    // 8) out_proj: fused A16_out (+ext) from y; fused W16_out (+ext)
    fused_y16_kernel<<<BL, 256, 0, stream>>>(delta, lA_out, A16_out, KP_OUT);
    cvt16w_ext_kernel<<<1024, 256, 0, stream>>>(w_out, lB_out, mask_out, 2048, KP_OUT, 64, W16_out);
    // 9) out_proj fp16 split-K=2 -> partials in dead delta region, then reduce
    float* P = delta;   // y consumed by fused_y16
    mfma_gemm16<0><<<dim3(8, 32, 2), 256, 0, stream>>>(
        A16_out, W16_out, KP_OUT, P, 1024, nullptr, 1024, KH_OUT);
    sk2_reduce_kernel<<<(4096 * 1024) / 256, 256, 0, stream>>>(P, (float*)d_out, 4096 * 1024);
}